// Round 6
// baseline (635.429 us; speedup 1.0000x reference)
//
#include <hip/hip_runtime.h>

#define D_MODEL 256
#define NSEQ    8192
#define PV_GROUPS 8

typedef _Float16 half8 __attribute__((ext_vector_type(8)));
typedef _Float16 half4 __attribute__((ext_vector_type(4)));
typedef float    f32x4 __attribute__((ext_vector_type(4)));

__device__ __forceinline__ half8 cvt8(f32x4 a, f32x4 b) {
  half8 h;
  h[0]=(_Float16)a[0]; h[1]=(_Float16)a[1]; h[2]=(_Float16)a[2]; h[3]=(_Float16)a[3];
  h[4]=(_Float16)b[0]; h[5]=(_Float16)b[1]; h[6]=(_Float16)b[2]; h[7]=(_Float16)b[3];
  return h;
}

__device__ __forceinline__ half8 load8_f32(const float* p) {
  f32x4 a = *(const f32x4*)p;
  f32x4 b = *(const f32x4*)(p + 4);
  return cvt8(a, b);
}

// ---------------------------------------------------------------------------
// P16F fragment-tiled layout for unnormalized p:
//   tile (tq = q>>4, tj = j>>5), 1KB each, linear index tq*256 + tj.
//   within tile: half index = L*8 + e, L = ((j>>3)&3)*16 + (q&15), e = j&7.
// A wave reading half8 at [tile_base + lane*8] holds exactly the
// mfma_16x16x32_f16 A-fragment. Row-contiguous access (row q, j-octet g) is
// the contiguous half8 at [((g&3)*16 + (q&15))*8] of tile (q>>4, g>>2).
// ---------------------------------------------------------------------------

// ---------------------------------------------------------------------------
// k1: QKV = x @ W^T. 1-wave blocks, grid (128,12) = 1536 resident waves.
// ---------------------------------------------------------------------------
__global__ __launch_bounds__(64, 3) void qkv_kernel(
    const float* __restrict__ x, const float* __restrict__ Wq,
    const float* __restrict__ Wk, const float* __restrict__ Wv,
    _Float16* __restrict__ QK16, _Float16* __restrict__ VT)
{
  const int lane = threadIdx.x & 63;
  const int c    = lane & 15;
  const int quad = lane >> 4;
  const int M0   = blockIdx.x * 64;
  const int Nblk = blockIdx.y * 64;                      // 0..704
  const int widx = Nblk >> 8;                            // 0=Q,1=K,2=V
  const int nloc = Nblk & 255;
  const float* W = (widx == 0) ? Wq : (widx == 1 ? Wk : Wv);

  f32x4 acc[4][4] = {};
  for (int k0 = 0; k0 < D_MODEL; k0 += 32) {
    half8 af[4], bf[4];
#pragma unroll
    for (int mt = 0; mt < 4; ++mt)
      af[mt] = load8_f32(&x[(size_t)(M0 + mt*16 + c) * D_MODEL + k0 + quad*8]);
#pragma unroll
    for (int nt = 0; nt < 4; ++nt)
      bf[nt] = load8_f32(&W[(size_t)(nloc + nt*16 + c) * D_MODEL + k0 + quad*8]);
#pragma unroll
    for (int mt = 0; mt < 4; ++mt)
#pragma unroll
      for (int nt = 0; nt < 4; ++nt)
        acc[mt][nt] = __builtin_amdgcn_mfma_f32_16x16x32_f16(af[mt], bf[nt], acc[mt][nt], 0, 0, 0);
  }

  if (widx < 2) {
#pragma unroll
    for (int mt = 0; mt < 4; ++mt)
#pragma unroll
      for (int nt = 0; nt < 4; ++nt) {
        const int col  = widx * 256 + nloc + nt*16 + c;
        const int row0 = M0 + mt*16 + quad*4;
#pragma unroll
        for (int r = 0; r < 4; ++r)
          QK16[(size_t)(row0 + r) * 512 + col] = (_Float16)acc[mt][nt][r];
      }
  } else {
#pragma unroll
    for (int mt = 0; mt < 4; ++mt)
#pragma unroll
      for (int nt = 0; nt < 4; ++nt) {
        const int d  = nloc + nt*16 + c;
        const int m0 = M0 + mt*16 + quad*4;
        half4 h;
        h[0]=(_Float16)acc[mt][nt][0]; h[1]=(_Float16)acc[mt][nt][1];
        h[2]=(_Float16)acc[mt][nt][2]; h[3]=(_Float16)acc[mt][nt][3];
        *(half4*)&VT[(size_t)d * NSEQ + m0] = h;
      }
  }
}

// ---------------------------------------------------------------------------
// k2: p = exp(Q@K^T / 16), row sums into lsum.
// P16=true:  write p16 in P16F fragment-tiled layout (sector-clean: each 1KB
//            tile written entirely by one wave).
// P16=false: legacy row-major f32 into attn (fallback path).
// ---------------------------------------------------------------------------
template<bool P16>
__global__ __launch_bounds__(256, 3) void score_kernel(
    const _Float16* __restrict__ QK16, void* __restrict__ Pout,
    float* __restrict__ lsum)
{
  const int tid  = threadIdx.x;
  const int lane = tid & 63;
  const int wave = tid >> 6;
  const int c    = lane & 15;
  const int quad = lane >> 4;
  const int M0   = blockIdx.x * 128 + (wave >> 1) * 64;
  const int N0   = blockIdx.y * 128 + (wave & 1) * 64;

  f32x4 acc[4][4] = {};
  half8 afA[4], bfA[4], afB[4], bfB[4];

  auto ld = [&](half8 (&af)[4], half8 (&bf)[4], int k0) {
#pragma unroll
    for (int mt = 0; mt < 4; ++mt)
      af[mt] = *(const half8*)&QK16[(size_t)(M0 + mt*16 + c) * 512 + k0 + quad*8];
#pragma unroll
    for (int nt = 0; nt < 4; ++nt)
      bf[nt] = *(const half8*)&QK16[(size_t)(N0 + nt*16 + c) * 512 + 256 + k0 + quad*8];
  };
  auto mm = [&](half8 (&af)[4], half8 (&bf)[4]) {
#pragma unroll
    for (int mt = 0; mt < 4; ++mt)
#pragma unroll
      for (int nt = 0; nt < 4; ++nt)
        acc[mt][nt] = __builtin_amdgcn_mfma_f32_16x16x32_f16(af[mt], bf[nt], acc[mt][nt], 0, 0, 0);
  };

  ld(afA, bfA, 0);
#pragma unroll
  for (int k0 = 0; k0 < 256; k0 += 64) {
    ld(afB, bfB, k0 + 32);
    mm(afA, bfA);
    if (k0 + 64 < 256) ld(afA, bfA, k0 + 64);
    mm(afB, bfB);
  }

  float psum[4][4] = {};   // [mt][r] partial row sums
#pragma unroll
  for (int mt = 0; mt < 4; ++mt) {
    const size_t tq = (size_t)((M0 + mt*16) >> 4);
#pragma unroll
    for (int nt = 0; nt < 4; ++nt) {
      // P16F base for this (mt,nt) fragment block, this lane:
      const size_t tj   = (size_t)((N0 >> 5) + (nt >> 1));
      const size_t base = (tq * 256 + tj) * 512
                        + (size_t)(((nt*2 + (c>>3)) & 3) * 128 + quad*32 + (c & 7));
#pragma unroll
      for (int r = 0; r < 4; ++r) {
        const float p = __expf(acc[mt][nt][r] * 0.0625f);
        psum[mt][r] += p;
        if constexpr (P16) {
          ((_Float16*)Pout)[base + r*8] = (_Float16)p;
        } else {
          const size_t idx = (size_t)(M0 + mt*16 + quad*4 + r) * NSEQ + N0 + nt*16 + c;
          ((float*)Pout)[idx] = p;
        }
      }
    }
  }

#pragma unroll
  for (int mt = 0; mt < 4; ++mt)
#pragma unroll
    for (int r = 0; r < 4; ++r) {
      float v = psum[mt][r];
      v += __shfl_xor(v, 1);
      v += __shfl_xor(v, 2);
      v += __shfl_xor(v, 4);
      v += __shfl_xor(v, 8);
      if (c == 0) atomicAdd(&lsum[M0 + mt*16 + quad*4 + r], v);
    }
}

// ---------------------------------------------------------------------------
// k3 (P16F path): attn = p/lsum written once; cntx += (p@V)/lsum.
// BARRIER-FREE, LDS-FREE rewrite. R5 post-mortem: per-iter cost was ~12K cyc
// because __syncthreads => s_waitcnt vmcnt(0) drained the just-issued stage
// AND the attn store acks every iteration (4-wave convoy, ~zero reads in
// flight most of the time, 2.0 TB/s). The P16F layout makes LDS pointless:
//   - A-frags  = direct contiguous half8 global loads (tile_base + lane*8)
//   - attn src = direct contiguous half8 global load of the same L2-hot tile
// So: loads + MFMA + independent attn stores, no sync at all. ~20 waves/CU
// each with ~12KB reads in flight => HBM-saturated (Little's law needs ~5KB).
// 4-wave redundant af reads hit the same-XCD L2.
// ---------------------------------------------------------------------------
__global__ __launch_bounds__(256) void pv_kernel_p16(
    const _Float16* __restrict__ P16F, float* __restrict__ attn,
    const float* __restrict__ lsum, const _Float16* __restrict__ VT,
    float* __restrict__ cntx)
{
  const int tid  = threadIdx.x;
  const int lane = tid & 63;
  const int wave = tid >> 6;
  const int c    = lane & 15;
  const int quad = lane >> 4;
  const int M0   = blockIdx.x * 32;
  const int jb   = blockIdx.y * (NSEQ / PV_GROUPS);
  const int je   = jb + NSEQ / PV_GROUPS;
  const int D0   = wave * 64;           // this wave's 64 output d-cols
  const int nq   = tid >> 3;            // attn-write row 0..31
  const int ng   = tid & 7;             // attn-write j-octet 0..7

  const float nscale = 1.0f / lsum[M0 + nq];   // one global load, L2-hot

  // P16F tile-row bases (tiles are 512 halves = 1KB)
  const size_t tqA = (size_t)(M0 >> 4);          // af tiles: rows (tqA+mt)
  const size_t tqN = (size_t)((M0 + nq) >> 4);   // attn-src tile row
  const int    ofsN = ((ng & 3) * 16 + ((M0 + nq) & 15)) * 8;

  f32x4 acc[2][4] = {};
  for (int j0 = jb; j0 < je; j0 += 64) {
    const size_t tj0 = (size_t)(j0 >> 5);

    // A-frags: direct from P16F (each tile = one fully-coalesced 1KB read)
    half8 af[2][2];
#pragma unroll
    for (int mt = 0; mt < 2; ++mt)
#pragma unroll
      for (int ks = 0; ks < 2; ++ks)
        af[mt][ks] = *(const half8*)&P16F[((tqA + mt) * 256 + tj0 + ks) * 512 + lane * 8];

    // B-frags: VT rows (L2/L3-hot, 4MB total)
    half8 bf[4][2];
#pragma unroll
    for (int ks = 0; ks < 2; ++ks)
#pragma unroll
      for (int nt = 0; nt < 4; ++nt)
        bf[nt][ks] = *(const half8*)&VT[(size_t)(D0 + nt*16 + c) * NSEQ + j0 + ks*32 + quad*8];

    // attn write: row-contiguous half8 from the (L2-hot) P16F tile, scaled.
    // Independent of the MFMA chain; full 256B sectors per wave.
    {
      const half8 v = *(const half8*)&P16F[(tqN * 256 + tj0 + (ng >> 2)) * 512 + ofsN];
      f32x4 w0, w1;
#pragma unroll
      for (int r = 0; r < 4; ++r) {
        w0[r] = (float)v[r]     * nscale;
        w1[r] = (float)v[r + 4] * nscale;
      }
      float* ar = attn + (size_t)(M0 + nq) * NSEQ + j0 + ng*8;
      *(f32x4*)ar       = w0;
      *(f32x4*)(ar + 4) = w1;
    }

    // PV MFMA (unnormalized accumulate)
#pragma unroll
    for (int ks = 0; ks < 2; ++ks)
#pragma unroll
      for (int mt = 0; mt < 2; ++mt)
#pragma unroll
        for (int nt = 0; nt < 4; ++nt)
          acc[mt][nt] = __builtin_amdgcn_mfma_f32_16x16x32_f16(af[mt][ks], bf[nt][ks], acc[mt][nt], 0, 0, 0);
  }

  // epilogue: scale by 1/lsum (direct L2-hot loads), accumulate into cntx
#pragma unroll
  for (int mt = 0; mt < 2; ++mt)
#pragma unroll
    for (int r = 0; r < 4; ++r) {
      const float s = 1.0f / lsum[M0 + mt*16 + quad*4 + r];
#pragma unroll
      for (int nt = 0; nt < 4; ++nt)
        atomicAdd(&cntx[(size_t)(M0 + mt*16 + quad*4 + r) * D_MODEL + D0 + nt*16 + c],
                  acc[mt][nt][r] * s);
    }
}

// ---------------------------------------------------------------------------
// k3 fallback (small ws): in-place f32 normalize + PV, unchanged semantics.
// ---------------------------------------------------------------------------
__global__ __launch_bounds__(256) void pv_kernel_f32(
    const float* __restrict__ Pin, float* __restrict__ attn,
    const float* __restrict__ lsum, const _Float16* __restrict__ VT,
    float* __restrict__ cntx)
{
  __shared__ float linv[32];
  const int tid  = threadIdx.x;
  const int lane = tid & 63;
  const int wave = tid >> 6;
  const int c    = lane & 15;
  const int quad = lane >> 4;
  const int M0   = blockIdx.x * 32;
  const int jb   = blockIdx.y * (NSEQ / PV_GROUPS);
  const int je   = jb + NSEQ / PV_GROUPS;
  const int D0   = wave * 64;
  const int nr   = tid >> 3;
  const int ncol = (tid & 7) * 8;

  if (tid < 32) linv[tid] = 1.0f / lsum[M0 + tid];
  __syncthreads();
  const float nscale = linv[nr];

  f32x4 acc[2][4] = {};
  for (int j0 = jb; j0 < je; j0 += 64) {
    const float* pr = Pin + (size_t)(M0 + nr) * NSEQ + j0 + ncol;
    f32x4 np0 = *(const f32x4*)pr;
    f32x4 np1 = *(const f32x4*)(pr + 4);

    half8 af[2][2], bf[4][2];
#pragma unroll
    for (int h = 0; h < 2; ++h) {
#pragma unroll
      for (int mt = 0; mt < 2; ++mt) {
        const float* pa = Pin + (size_t)(M0 + mt*16 + c) * NSEQ + j0 + h*32 + quad*8;
        af[mt][h] = cvt8(*(const f32x4*)pa, *(const f32x4*)(pa + 4));
      }
#pragma unroll
      for (int nt = 0; nt < 4; ++nt)
        bf[nt][h] = *(const half8*)&VT[(size_t)(D0 + nt*16 + c) * NSEQ + j0 + h*32 + quad*8];
    }

    __syncthreads();   // all reads of this tile before in-place writes

    float* ar = attn + (size_t)(M0 + nr) * NSEQ + j0 + ncol;
    *(f32x4*)ar       = np0 * nscale;
    *(f32x4*)(ar + 4) = np1 * nscale;

#pragma unroll
    for (int h = 0; h < 2; ++h)
#pragma unroll
      for (int mt = 0; mt < 2; ++mt)
#pragma unroll
        for (int nt = 0; nt < 4; ++nt)
          acc[mt][nt] = __builtin_amdgcn_mfma_f32_16x16x32_f16(af[mt][h], bf[nt][h], acc[mt][nt], 0, 0, 0);
  }

#pragma unroll
  for (int mt = 0; mt < 2; ++mt)
#pragma unroll
    for (int r = 0; r < 4; ++r) {
      const float s = linv[mt*16 + quad*4 + r];
#pragma unroll
      for (int nt = 0; nt < 4; ++nt)
        atomicAdd(&cntx[(size_t)(M0 + mt*16 + quad*4 + r) * D_MODEL + D0 + nt*16 + c],
                  acc[mt][nt][r] * s);
    }
}

// ---------------------------------------------------------------------------
extern "C" void kernel_launch(void* const* d_in, const int* in_sizes, int n_in,
                              void* d_out, int out_size, void* d_ws, size_t ws_size,
                              hipStream_t stream)
{
  const float* x  = (const float*)d_in[0];
  const float* Wq = (const float*)d_in[1];
  const float* Wk = (const float*)d_in[2];
  const float* Wv = (const float*)d_in[3];

  float* cntx = (float*)d_out;                         // [8192 x 256]
  float* attn = cntx + (size_t)NSEQ * D_MODEL;         // [8192 x 8192]

  // ws layout: QK16 (8MB) | VT (4MB) | lsum (32KB) | P16F (128MB, if room)
  _Float16* QK16 = (_Float16*)d_ws;
  _Float16* VT   = QK16 + (size_t)NSEQ * 512;
  float*    lsum = (float*)(VT + (size_t)D_MODEL * NSEQ);
  _Float16* P16F = (_Float16*)(lsum + NSEQ);

  const size_t base_bytes = (size_t)NSEQ*512*2 + (size_t)D_MODEL*NSEQ*2 + (size_t)NSEQ*4;
  const bool big_ws = ws_size >= base_bytes + (size_t)NSEQ * NSEQ * 2;

  hipMemsetAsync(cntx, 0, sizeof(float) * (size_t)NSEQ * D_MODEL, stream);
  hipMemsetAsync(lsum, 0, sizeof(float) * NSEQ, stream);

  qkv_kernel<<<dim3(128, 12), 64, 0, stream>>>(x, Wq, Wk, Wv, QK16, VT);

  if (big_ws) {
    score_kernel<true><<<dim3(64, 64), 256, 0, stream>>>(QK16, (void*)P16F, lsum);
    pv_kernel_p16<<<dim3(NSEQ/32, PV_GROUPS), 256, 0, stream>>>(P16F, attn, lsum, VT, cntx);
  } else {
    score_kernel<false><<<dim3(64, 64), 256, 0, stream>>>(QK16, (void*)attn, lsum);
    pv_kernel_f32<<<dim3(NSEQ/32, PV_GROUPS), 256, 0, stream>>>(attn, attn, lsum, VT, cntx);
  }
}

// Round 7
// 557.782 us; speedup vs baseline: 1.1392x; 1.1392x over previous
//
#include <hip/hip_runtime.h>

#define D_MODEL 256
#define NSEQ    8192
#define PV_GROUPS 8

typedef _Float16 half8 __attribute__((ext_vector_type(8)));
typedef _Float16 half4 __attribute__((ext_vector_type(4)));
typedef float    f32x4 __attribute__((ext_vector_type(4)));

typedef __attribute__((address_space(1))) const void* gptr_t;
typedef __attribute__((address_space(3))) void*       lptr_t;

__device__ __forceinline__ half8 cvt8(f32x4 a, f32x4 b) {
  half8 h;
  h[0]=(_Float16)a[0]; h[1]=(_Float16)a[1]; h[2]=(_Float16)a[2]; h[3]=(_Float16)a[3];
  h[4]=(_Float16)b[0]; h[5]=(_Float16)b[1]; h[6]=(_Float16)b[2]; h[7]=(_Float16)b[3];
  return h;
}

__device__ __forceinline__ half8 load8_f32(const float* p) {
  f32x4 a = *(const f32x4*)p;
  f32x4 b = *(const f32x4*)(p + 4);
  return cvt8(a, b);
}

// ---------------------------------------------------------------------------
// P16F fragment-tiled layout for unnormalized p:
//   tile (tq = q>>4, tj = j>>5), 1KB each, linear index tq*256 + tj.
//   within tile: half index = L*8 + e, L = ((j>>3)&3)*16 + (q&15), e = j&7.
// A wave reading half8 at [tile_base + lane*8] holds exactly the
// mfma_16x16x32_f16 A-fragment. Row-contiguous access (row q, j-octet g) is
// the contiguous half8 at [((g&3)*16 + (q&15))*8] of tile (q>>4, g>>2).
// ---------------------------------------------------------------------------

// ---------------------------------------------------------------------------
// k1: QKV = x @ W^T. 32x32 wave tiles, 1-wave blocks, grid (256,24) = 6144
// blocks = 24 waves/CU (was 6 — latency-starved, ~190us suspected).
// ---------------------------------------------------------------------------
__global__ __launch_bounds__(64, 6) void qkv_kernel(
    const float* __restrict__ x, const float* __restrict__ Wq,
    const float* __restrict__ Wk, const float* __restrict__ Wv,
    _Float16* __restrict__ QK16, _Float16* __restrict__ VT)
{
  const int lane = threadIdx.x & 63;
  const int c    = lane & 15;
  const int quad = lane >> 4;
  const int M0   = blockIdx.x * 32;
  const int widx = blockIdx.y >> 3;                      // 0=Q,1=K,2=V
  const int nloc = (blockIdx.y & 7) * 32;
  const float* W = (widx == 0) ? Wq : (widx == 1 ? Wk : Wv);

  f32x4 acc[2][2] = {};
  for (int k0 = 0; k0 < D_MODEL; k0 += 32) {
    half8 af[2], bf[2];
#pragma unroll
    for (int mt = 0; mt < 2; ++mt)
      af[mt] = load8_f32(&x[(size_t)(M0 + mt*16 + c) * D_MODEL + k0 + quad*8]);
#pragma unroll
    for (int nt = 0; nt < 2; ++nt)
      bf[nt] = load8_f32(&W[(size_t)(nloc + nt*16 + c) * D_MODEL + k0 + quad*8]);
#pragma unroll
    for (int mt = 0; mt < 2; ++mt)
#pragma unroll
      for (int nt = 0; nt < 2; ++nt)
        acc[mt][nt] = __builtin_amdgcn_mfma_f32_16x16x32_f16(af[mt], bf[nt], acc[mt][nt], 0, 0, 0);
  }

  if (widx < 2) {
#pragma unroll
    for (int mt = 0; mt < 2; ++mt)
#pragma unroll
      for (int nt = 0; nt < 2; ++nt) {
        const int col  = widx * 256 + nloc + nt*16 + c;
        const int row0 = M0 + mt*16 + quad*4;
#pragma unroll
        for (int r = 0; r < 4; ++r)
          QK16[(size_t)(row0 + r) * 512 + col] = (_Float16)acc[mt][nt][r];
      }
  } else {
#pragma unroll
    for (int mt = 0; mt < 2; ++mt)
#pragma unroll
      for (int nt = 0; nt < 2; ++nt) {
        const int d  = nloc + nt*16 + c;
        const int m0 = M0 + mt*16 + quad*4;
        half4 h;
        h[0]=(_Float16)acc[mt][nt][0]; h[1]=(_Float16)acc[mt][nt][1];
        h[2]=(_Float16)acc[mt][nt][2]; h[3]=(_Float16)acc[mt][nt][3];
        *(half4*)&VT[(size_t)d * NSEQ + m0] = h;
      }
  }
}

// ---------------------------------------------------------------------------
// k2: p = exp(Q@K^T / 16), row sums into lsum. REBUILT: m97 2-phase
// global_load_lds pipeline (R2 showed reg-dbuf collapses: VGPR=84).
// Q/K tiles staged DIRECTLY in MFMA-fragment order (per-lane global src:
// row (l&15), k-octet (l>>4)) -> LDS reads are conflict-free ds_read_b128.
// Block 128x128, 4 waves (2x2 of 64x64), grid (64,64).
// ---------------------------------------------------------------------------
template<bool P16>
__global__ __launch_bounds__(256) void score_kernel(
    const _Float16* __restrict__ QK16, void* __restrict__ Pout,
    float* __restrict__ lsum)
{
  __shared__ alignas(16) _Float16 Qs[2][8][512];
  __shared__ alignas(16) _Float16 Ks[2][8][512];
  const int tid  = threadIdx.x;
  const int lane = tid & 63;
  const int wave = tid >> 6;
  const int c    = lane & 15;
  const int quad = lane >> 4;
  const int wr   = wave >> 1;
  const int wc   = wave & 1;
  const int M0   = blockIdx.x * 128;
  const int N0   = blockIdx.y * 128;
  const int mb   = M0 + wr * 64;        // this wave's 64x64 output origin
  const int nb   = N0 + wc * 64;

  auto stage = [&](int buf, int k0) {
#pragma unroll
    for (int s = 0; s < 2; ++s) {
      const int t = wave * 2 + s;
      const _Float16* qsrc = &QK16[(size_t)(M0 + t*16 + (lane & 15)) * 512 + k0 + (lane >> 4) * 8];
      __builtin_amdgcn_global_load_lds((gptr_t)qsrc, (lptr_t)&Qs[buf][t][0], 16, 0, 0);
      const _Float16* ksrc = &QK16[(size_t)(N0 + t*16 + (lane & 15)) * 512 + 256 + k0 + (lane >> 4) * 8];
      __builtin_amdgcn_global_load_lds((gptr_t)ksrc, (lptr_t)&Ks[buf][t][0], 16, 0, 0);
    }
  };

  f32x4 acc[4][4] = {};
  stage(0, 0);
  __syncthreads();
  for (int it = 0; it < 8; ++it) {
    const int buf = it & 1;
    if (it < 7) stage(buf ^ 1, (it + 1) * 32);
    half8 af[4], bf[4];
#pragma unroll
    for (int mt = 0; mt < 4; ++mt)
      af[mt] = *(const half8*)&Qs[buf][wr*4 + mt][lane * 8];
#pragma unroll
    for (int nt = 0; nt < 4; ++nt)
      bf[nt] = *(const half8*)&Ks[buf][wc*4 + nt][lane * 8];
#pragma unroll
    for (int mt = 0; mt < 4; ++mt)
#pragma unroll
      for (int nt = 0; nt < 4; ++nt)
        acc[mt][nt] = __builtin_amdgcn_mfma_f32_16x16x32_f16(af[mt], bf[nt], acc[mt][nt], 0, 0, 0);
    __syncthreads();
  }

  float psum[4][4] = {};   // [mt][r] partial row sums
#pragma unroll
  for (int mt = 0; mt < 4; ++mt) {
    const size_t tq = (size_t)((mb >> 4) + mt);
#pragma unroll
    for (int nt = 0; nt < 4; ++nt) {
      const size_t tj   = (size_t)((nb >> 5) + (nt >> 1));
      const size_t base = (tq * 256 + tj) * 512
                        + (size_t)(((nt*2 + (c>>3)) & 3) * 128 + quad*32 + (c & 7));
#pragma unroll
      for (int r = 0; r < 4; ++r) {
        const float p = __expf(acc[mt][nt][r] * 0.0625f);
        psum[mt][r] += p;
        if constexpr (P16) {
          ((_Float16*)Pout)[base + r*8] = (_Float16)p;
        } else {
          const size_t idx = (size_t)(mb + mt*16 + quad*4 + r) * NSEQ + nb + nt*16 + c;
          ((float*)Pout)[idx] = p;
        }
      }
    }
  }

#pragma unroll
  for (int mt = 0; mt < 4; ++mt)
#pragma unroll
    for (int r = 0; r < 4; ++r) {
      float v = psum[mt][r];
      v += __shfl_xor(v, 1);
      v += __shfl_xor(v, 2);
      v += __shfl_xor(v, 4);
      v += __shfl_xor(v, 8);
      if (c == 0) atomicAdd(&lsum[mb + mt*16 + quad*4 + r], v);
    }
}

// ---------------------------------------------------------------------------
// k3a: pv_gemm — cpart[gy] = p @ V over this group's K-range. PURE GEMM:
// no attn writes, no atomics, no normalize. m97 2-phase gload_lds staging of
// P16F tiles (linear LDS, conflict-free b128). Block 64 rows x 256 cols,
// 4 waves (each owns 64 d-cols), grid (128, g).
// ---------------------------------------------------------------------------
__global__ __launch_bounds__(256) void pv_gemm_kernel(
    const _Float16* __restrict__ P16F, const _Float16* __restrict__ VT,
    float* __restrict__ cpart, int jlen)
{
  __shared__ alignas(16) _Float16 As[2][8][512];
  const int tid  = threadIdx.x;
  const int lane = tid & 63;
  const int wave = tid >> 6;
  const int c    = lane & 15;
  const int quad = lane >> 4;
  const int M0   = blockIdx.x * 64;
  const int gy   = blockIdx.y;
  const int jb   = gy * jlen;
  const int D0   = wave * 64;
  const size_t tqA = (size_t)(M0 >> 4);

  auto stage = [&](int buf, int j0) {
    const size_t tj0 = (size_t)(j0 >> 5);
#pragma unroll
    for (int s = 0; s < 2; ++s) {
      const int t = wave * 2 + s;          // t = mt*2 + ks
      const _Float16* src = &P16F[((tqA + (t >> 1)) * 256 + tj0 + (t & 1)) * 512 + lane * 8];
      __builtin_amdgcn_global_load_lds((gptr_t)src, (lptr_t)&As[buf][t][0], 16, 0, 0);
    }
  };

  f32x4 acc[4][4] = {};
  stage(0, jb);
  __syncthreads();
  const int iters = jlen >> 6;
  for (int it = 0; it < iters; ++it) {
    const int buf = it & 1;
    const int j0  = jb + it * 64;
    if (it + 1 < iters) stage(buf ^ 1, j0 + 64);

    half8 af[4][2];
#pragma unroll
    for (int mt = 0; mt < 4; ++mt)
#pragma unroll
      for (int ks = 0; ks < 2; ++ks)
        af[mt][ks] = *(const half8*)&As[buf][mt*2 + ks][lane * 8];

    half8 bf[4][2];
#pragma unroll
    for (int ks = 0; ks < 2; ++ks)
#pragma unroll
      for (int nt = 0; nt < 4; ++nt)
        bf[nt][ks] = *(const half8*)&VT[(size_t)(D0 + nt*16 + c) * NSEQ + j0 + ks*32 + quad*8];

#pragma unroll
    for (int ks = 0; ks < 2; ++ks)
#pragma unroll
      for (int mt = 0; mt < 4; ++mt)
#pragma unroll
        for (int nt = 0; nt < 4; ++nt)
          acc[mt][nt] = __builtin_amdgcn_mfma_f32_16x16x32_f16(af[mt][ks], bf[nt][ks], acc[mt][nt], 0, 0, 0);
    __syncthreads();
  }

  float* out = cpart + (size_t)gy * NSEQ * D_MODEL;
#pragma unroll
  for (int mt = 0; mt < 4; ++mt)
#pragma unroll
    for (int nt = 0; nt < 4; ++nt)
#pragma unroll
      for (int r = 0; r < 4; ++r)
        out[(size_t)(M0 + mt*16 + quad*4 + r) * D_MODEL + D0 + nt*16 + c] = acc[mt][nt][r];
}

// ---------------------------------------------------------------------------
// k3b: norm — attn = p16 * (1/lsum[row]). Pure streaming kernel (G13):
// contiguous half8 reads from P16F, 512B-contiguous f32 row writes.
// Block: 16 rows x 1024 cols; grid (512, 8).
// ---------------------------------------------------------------------------
__global__ __launch_bounds__(256, 8) void norm_kernel(
    const _Float16* __restrict__ P16F, const float* __restrict__ lsum,
    float* __restrict__ attn)
{
  const int tid = threadIdx.x;
  const int q   = tid >> 4;              // 0..15
  const int gl  = tid & 15;
  const int bx  = blockIdx.x;            // row-tile tq 0..511
  const int j0  = blockIdx.y * 1024;

  const float nscale = 1.0f / lsum[bx*16 + q];
  const size_t tbase = (size_t)bx * 256 + (size_t)(j0 >> 5);

#pragma unroll
  for (int it = 0; it < 8; ++it) {
    const int g = gl + it * 16;          // j-octet 0..127
    const half8 v = *(const half8*)&P16F[(tbase + (g >> 2)) * 512 + ((g & 3) * 16 + q) * 8];
    f32x4 w0, w1;
#pragma unroll
    for (int r = 0; r < 4; ++r) {
      w0[r] = (float)v[r]     * nscale;
      w1[r] = (float)v[r + 4] * nscale;
    }
    float* ar = attn + (size_t)(bx*16 + q) * NSEQ + j0 + g*8;
    *(f32x4*)ar       = w0;
    *(f32x4*)(ar + 4) = w1;
  }
}

// ---------------------------------------------------------------------------
// k3c: reduce — cntx = (sum_g cpart[g]) * (1/lsum[row]).
// ---------------------------------------------------------------------------
__global__ __launch_bounds__(256, 8) void reduce_kernel(
    const float* __restrict__ cpart, const float* __restrict__ lsum,
    float* __restrict__ cntx, int g)
{
  const int idx4 = blockIdx.x * 256 + threadIdx.x;      // f32x4 index
  const int row  = idx4 >> 6;
  const float s  = 1.0f / lsum[row];
  f32x4 v = {};
  for (int gi = 0; gi < g; ++gi)
    v += *(const f32x4*)&cpart[(size_t)gi * NSEQ * D_MODEL + (size_t)idx4 * 4];
  *(f32x4*)&cntx[(size_t)idx4 * 4] = v * s;
}

// ---------------------------------------------------------------------------
// Tier B fallback: R6 fused pv (atomics) — kept unchanged, known-passing.
// ---------------------------------------------------------------------------
__global__ __launch_bounds__(256) void pv_kernel_p16(
    const _Float16* __restrict__ P16F, float* __restrict__ attn,
    const float* __restrict__ lsum, const _Float16* __restrict__ VT,
    float* __restrict__ cntx)
{
  const int tid  = threadIdx.x;
  const int lane = tid & 63;
  const int wave = tid >> 6;
  const int c    = lane & 15;
  const int quad = lane >> 4;
  const int M0   = blockIdx.x * 32;
  const int jb   = blockIdx.y * (NSEQ / PV_GROUPS);
  const int je   = jb + NSEQ / PV_GROUPS;
  const int D0   = wave * 64;
  const int nq   = tid >> 3;
  const int ng   = tid & 7;

  const float nscale = 1.0f / lsum[M0 + nq];
  const size_t tqA = (size_t)(M0 >> 4);
  const size_t tqN = (size_t)((M0 + nq) >> 4);
  const int    ofsN = ((ng & 3) * 16 + ((M0 + nq) & 15)) * 8;

  f32x4 acc[2][4] = {};
  for (int j0 = jb; j0 < je; j0 += 64) {
    const size_t tj0 = (size_t)(j0 >> 5);
    half8 af[2][2];
#pragma unroll
    for (int mt = 0; mt < 2; ++mt)
#pragma unroll
      for (int ks = 0; ks < 2; ++ks)
        af[mt][ks] = *(const half8*)&P16F[((tqA + mt) * 256 + tj0 + ks) * 512 + lane * 8];
    half8 bf[4][2];
#pragma unroll
    for (int ks = 0; ks < 2; ++ks)
#pragma unroll
      for (int nt = 0; nt < 4; ++nt)
        bf[nt][ks] = *(const half8*)&VT[(size_t)(D0 + nt*16 + c) * NSEQ + j0 + ks*32 + quad*8];
    {
      const half8 v = *(const half8*)&P16F[(tqN * 256 + tj0 + (ng >> 2)) * 512 + ofsN];
      f32x4 w0, w1;
#pragma unroll
      for (int r = 0; r < 4; ++r) {
        w0[r] = (float)v[r]     * nscale;
        w1[r] = (float)v[r + 4] * nscale;
      }
      float* ar = attn + (size_t)(M0 + nq) * NSEQ + j0 + ng*8;
      *(f32x4*)ar       = w0;
      *(f32x4*)(ar + 4) = w1;
    }
#pragma unroll
    for (int ks = 0; ks < 2; ++ks)
#pragma unroll
      for (int mt = 0; mt < 2; ++mt)
#pragma unroll
        for (int nt = 0; nt < 4; ++nt)
          acc[mt][nt] = __builtin_amdgcn_mfma_f32_16x16x32_f16(af[mt][ks], bf[nt][ks], acc[mt][nt], 0, 0, 0);
  }

#pragma unroll
  for (int mt = 0; mt < 2; ++mt)
#pragma unroll
    for (int r = 0; r < 4; ++r) {
      const float s = 1.0f / lsum[M0 + mt*16 + quad*4 + r];
#pragma unroll
      for (int nt = 0; nt < 4; ++nt)
        atomicAdd(&cntx[(size_t)(M0 + mt*16 + quad*4 + r) * D_MODEL + D0 + nt*16 + c],
                  acc[mt][nt][r] * s);
    }
}

// ---------------------------------------------------------------------------
// Tier C fallback (small ws): in-place f32 normalize + PV.
// ---------------------------------------------------------------------------
__global__ __launch_bounds__(256) void pv_kernel_f32(
    const float* __restrict__ Pin, float* __restrict__ attn,
    const float* __restrict__ lsum, const _Float16* __restrict__ VT,
    float* __restrict__ cntx)
{
  __shared__ float linv[32];
  const int tid  = threadIdx.x;
  const int lane = tid & 63;
  const int wave = tid >> 6;
  const int c    = lane & 15;
  const int quad = lane >> 4;
  const int M0   = blockIdx.x * 32;
  const int jb   = blockIdx.y * (NSEQ / PV_GROUPS);
  const int je   = jb + NSEQ / PV_GROUPS;
  const int D0   = wave * 64;
  const int nr   = tid >> 3;
  const int ncol = (tid & 7) * 8;

  if (tid < 32) linv[tid] = 1.0f / lsum[M0 + tid];
  __syncthreads();
  const float nscale = linv[nr];

  f32x4 acc[2][4] = {};
  for (int j0 = jb; j0 < je; j0 += 64) {
    const float* pr = Pin + (size_t)(M0 + nr) * NSEQ + j0 + ncol;
    f32x4 np0 = *(const f32x4*)pr;
    f32x4 np1 = *(const f32x4*)(pr + 4);

    half8 af[2][2], bf[4][2];
#pragma unroll
    for (int h = 0; h < 2; ++h) {
#pragma unroll
      for (int mt = 0; mt < 2; ++mt) {
        const float* pa = Pin + (size_t)(M0 + mt*16 + c) * NSEQ + j0 + h*32 + quad*8;
        af[mt][h] = cvt8(*(const f32x4*)pa, *(const f32x4*)(pa + 4));
      }
#pragma unroll
      for (int nt = 0; nt < 4; ++nt)
        bf[nt][h] = *(const half8*)&VT[(size_t)(D0 + nt*16 + c) * NSEQ + j0 + h*32 + quad*8];
    }

    __syncthreads();

    float* ar = attn + (size_t)(M0 + nr) * NSEQ + j0 + ncol;
    *(f32x4*)ar       = np0 * nscale;
    *(f32x4*)(ar + 4) = np1 * nscale;

#pragma unroll
    for (int h = 0; h < 2; ++h)
#pragma unroll
      for (int mt = 0; mt < 2; ++mt)
#pragma unroll
        for (int nt = 0; nt < 4; ++nt)
          acc[mt][nt] = __builtin_amdgcn_mfma_f32_16x16x32_f16(af[mt][h], bf[nt][h], acc[mt][nt], 0, 0, 0);
  }

#pragma unroll
  for (int mt = 0; mt < 2; ++mt)
#pragma unroll
    for (int r = 0; r < 4; ++r) {
      const float s = linv[mt*16 + quad*4 + r];
#pragma unroll
      for (int nt = 0; nt < 4; ++nt)
        atomicAdd(&cntx[(size_t)(M0 + mt*16 + quad*4 + r) * D_MODEL + D0 + nt*16 + c],
                  acc[mt][nt][r] * s);
    }
}

// ---------------------------------------------------------------------------
extern "C" void kernel_launch(void* const* d_in, const int* in_sizes, int n_in,
                              void* d_out, int out_size, void* d_ws, size_t ws_size,
                              hipStream_t stream)
{
  const float* x  = (const float*)d_in[0];
  const float* Wq = (const float*)d_in[1];
  const float* Wk = (const float*)d_in[2];
  const float* Wv = (const float*)d_in[3];

  float* cntx = (float*)d_out;                         // [8192 x 256]
  float* attn = cntx + (size_t)NSEQ * D_MODEL;         // [8192 x 8192]

  // ws layout: QK16 (8MB) | VT (4MB) | lsum (32KB) | P16F (128MB) | cpart (g*8MB)
  _Float16* QK16 = (_Float16*)d_ws;
  _Float16* VT   = QK16 + (size_t)NSEQ * 512;
  float*    lsum = (float*)(VT + (size_t)D_MODEL * NSEQ);
  _Float16* P16F = (_Float16*)(lsum + NSEQ);
  float*    cpart = (float*)(P16F + (size_t)NSEQ * NSEQ);

  const size_t base_bytes = (size_t)NSEQ*512*2 + (size_t)D_MODEL*NSEQ*2 + (size_t)NSEQ*4;
  const size_t p16_bytes  = (size_t)NSEQ * NSEQ * 2;
  const size_t part_bytes = (size_t)NSEQ * D_MODEL * 4;   // 8MB per group

  int g = 0;
  for (int gt = 8; gt >= 2; gt >>= 1)
    if (ws_size >= base_bytes + p16_bytes + (size_t)gt * part_bytes) { g = gt; break; }
  const bool big_ws = ws_size >= base_bytes + p16_bytes;

  hipMemsetAsync(lsum, 0, sizeof(float) * NSEQ, stream);

  qkv_kernel<<<dim3(256, 24), 64, 0, stream>>>(x, Wq, Wk, Wv, QK16, VT);

  if (g >= 2) {
    // Tier A: no atomics, three clean-regime kernels
    score_kernel<true><<<dim3(64, 64), 256, 0, stream>>>(QK16, (void*)P16F, lsum);
    pv_gemm_kernel<<<dim3(128, g), 256, 0, stream>>>(P16F, VT, cpart, NSEQ / g);
    norm_kernel<<<dim3(512, 8), 256, 0, stream>>>(P16F, lsum, attn);
    reduce_kernel<<<dim3(NSEQ * D_MODEL / 1024), 256, 0, stream>>>(cpart, lsum, cntx, g);
  } else if (big_ws) {
    // Tier B: fused pv with atomics (R6 path)
    hipMemsetAsync(cntx, 0, sizeof(float) * (size_t)NSEQ * D_MODEL, stream);
    score_kernel<true><<<dim3(64, 64), 256, 0, stream>>>(QK16, (void*)P16F, lsum);
    pv_kernel_p16<<<dim3(NSEQ/32, PV_GROUPS), 256, 0, stream>>>(P16F, attn, lsum, VT, cntx);
  } else {
    // Tier C: f32 in-place path
    hipMemsetAsync(cntx, 0, sizeof(float) * (size_t)NSEQ * D_MODEL, stream);
    score_kernel<false><<<dim3(64, 64), 256, 0, stream>>>(QK16, (void*)attn, lsum);
    pv_kernel_f32<<<dim3(NSEQ/32, PV_GROUPS), 256, 0, stream>>>(attn, attn, lsum, VT, cntx);
  }
}

// Round 8
// 546.343 us; speedup vs baseline: 1.1631x; 1.0209x over previous
//
#include <hip/hip_runtime.h>

#define D_MODEL 256
#define NSEQ    8192
#define PV_GROUPS 8

typedef _Float16 half8 __attribute__((ext_vector_type(8)));
typedef _Float16 half4 __attribute__((ext_vector_type(4)));
typedef float    f32x4 __attribute__((ext_vector_type(4)));

typedef __attribute__((address_space(1))) const void* gptr_t;
typedef __attribute__((address_space(3))) void*       lptr_t;

__device__ __forceinline__ half8 cvt8(f32x4 a, f32x4 b) {
  half8 h;
  h[0]=(_Float16)a[0]; h[1]=(_Float16)a[1]; h[2]=(_Float16)a[2]; h[3]=(_Float16)a[3];
  h[4]=(_Float16)b[0]; h[5]=(_Float16)b[1]; h[6]=(_Float16)b[2]; h[7]=(_Float16)b[3];
  return h;
}

__device__ __forceinline__ half8 load8_f32(const float* p) {
  f32x4 a = *(const f32x4*)p;
  f32x4 b = *(const f32x4*)(p + 4);
  return cvt8(a, b);
}

// ---------------------------------------------------------------------------
// P16F fragment-tiled layout for unnormalized p:
//   tile (tq = q>>4, tj = j>>5), 1KB each, linear index tq*256 + tj.
//   within tile: half index = L*8 + e, L = ((j>>3)&3)*16 + (q&15), e = j&7.
// A wave reading half8 at [tile_base + lane*8] holds exactly the
// mfma_16x16x32_f16 A-fragment. Row-contiguous access (row q, j-octet g) is
// the contiguous half8 at [((g&3)*16 + (q&15))*8] of tile (q>>4, g>>2).
// ---------------------------------------------------------------------------

// ---------------------------------------------------------------------------
// k1: QKV = x @ W^T. 32x32 wave tiles, 1-wave blocks, grid (256,24) = 6144
// blocks = 24 waves/CU.
// ---------------------------------------------------------------------------
__global__ __launch_bounds__(64, 6) void qkv_kernel(
    const float* __restrict__ x, const float* __restrict__ Wq,
    const float* __restrict__ Wk, const float* __restrict__ Wv,
    _Float16* __restrict__ QK16, _Float16* __restrict__ VT)
{
  const int lane = threadIdx.x & 63;
  const int c    = lane & 15;
  const int quad = lane >> 4;
  const int M0   = blockIdx.x * 32;
  const int widx = blockIdx.y >> 3;                      // 0=Q,1=K,2=V
  const int nloc = (blockIdx.y & 7) * 32;
  const float* W = (widx == 0) ? Wq : (widx == 1 ? Wk : Wv);

  f32x4 acc[2][2] = {};
  for (int k0 = 0; k0 < D_MODEL; k0 += 32) {
    half8 af[2], bf[2];
#pragma unroll
    for (int mt = 0; mt < 2; ++mt)
      af[mt] = load8_f32(&x[(size_t)(M0 + mt*16 + c) * D_MODEL + k0 + quad*8]);
#pragma unroll
    for (int nt = 0; nt < 2; ++nt)
      bf[nt] = load8_f32(&W[(size_t)(nloc + nt*16 + c) * D_MODEL + k0 + quad*8]);
#pragma unroll
    for (int mt = 0; mt < 2; ++mt)
#pragma unroll
      for (int nt = 0; nt < 2; ++nt)
        acc[mt][nt] = __builtin_amdgcn_mfma_f32_16x16x32_f16(af[mt], bf[nt], acc[mt][nt], 0, 0, 0);
  }

  if (widx < 2) {
#pragma unroll
    for (int mt = 0; mt < 2; ++mt)
#pragma unroll
      for (int nt = 0; nt < 2; ++nt) {
        const int col  = widx * 256 + nloc + nt*16 + c;
        const int row0 = M0 + mt*16 + quad*4;
#pragma unroll
        for (int r = 0; r < 4; ++r)
          QK16[(size_t)(row0 + r) * 512 + col] = (_Float16)acc[mt][nt][r];
      }
  } else {
#pragma unroll
    for (int mt = 0; mt < 2; ++mt)
#pragma unroll
      for (int nt = 0; nt < 2; ++nt) {
        const int d  = nloc + nt*16 + c;
        const int m0 = M0 + mt*16 + quad*4;
        half4 h;
        h[0]=(_Float16)acc[mt][nt][0]; h[1]=(_Float16)acc[mt][nt][1];
        h[2]=(_Float16)acc[mt][nt][2]; h[3]=(_Float16)acc[mt][nt][3];
        *(half4*)&VT[(size_t)d * NSEQ + m0] = h;
      }
  }
}

// ---------------------------------------------------------------------------
// k2: p = exp(Q@K^T / 16), row sums into lsum. m97 2-phase global_load_lds
// pipeline, Q/K staged directly in MFMA-fragment order. Block 128x128,
// 4 waves, grid (64,64). (Unchanged from R7 — not in top-5.)
// ---------------------------------------------------------------------------
template<bool P16>
__global__ __launch_bounds__(256) void score_kernel(
    const _Float16* __restrict__ QK16, void* __restrict__ Pout,
    float* __restrict__ lsum)
{
  __shared__ alignas(16) _Float16 Qs[2][8][512];
  __shared__ alignas(16) _Float16 Ks[2][8][512];
  const int tid  = threadIdx.x;
  const int lane = tid & 63;
  const int wave = tid >> 6;
  const int c    = lane & 15;
  const int quad = lane >> 4;
  const int wr   = wave >> 1;
  const int wc   = wave & 1;
  const int M0   = blockIdx.x * 128;
  const int N0   = blockIdx.y * 128;
  const int mb   = M0 + wr * 64;
  const int nb   = N0 + wc * 64;

  auto stage = [&](int buf, int k0) {
#pragma unroll
    for (int s = 0; s < 2; ++s) {
      const int t = wave * 2 + s;
      const _Float16* qsrc = &QK16[(size_t)(M0 + t*16 + (lane & 15)) * 512 + k0 + (lane >> 4) * 8];
      __builtin_amdgcn_global_load_lds((gptr_t)qsrc, (lptr_t)&Qs[buf][t][0], 16, 0, 0);
      const _Float16* ksrc = &QK16[(size_t)(N0 + t*16 + (lane & 15)) * 512 + 256 + k0 + (lane >> 4) * 8];
      __builtin_amdgcn_global_load_lds((gptr_t)ksrc, (lptr_t)&Ks[buf][t][0], 16, 0, 0);
    }
  };

  f32x4 acc[4][4] = {};
  stage(0, 0);
  __syncthreads();
  for (int it = 0; it < 8; ++it) {
    const int buf = it & 1;
    if (it < 7) stage(buf ^ 1, (it + 1) * 32);
    half8 af[4], bf[4];
#pragma unroll
    for (int mt = 0; mt < 4; ++mt)
      af[mt] = *(const half8*)&Qs[buf][wr*4 + mt][lane * 8];
#pragma unroll
    for (int nt = 0; nt < 4; ++nt)
      bf[nt] = *(const half8*)&Ks[buf][wc*4 + nt][lane * 8];
#pragma unroll
    for (int mt = 0; mt < 4; ++mt)
#pragma unroll
      for (int nt = 0; nt < 4; ++nt)
        acc[mt][nt] = __builtin_amdgcn_mfma_f32_16x16x32_f16(af[mt], bf[nt], acc[mt][nt], 0, 0, 0);
    __syncthreads();
  }

  float psum[4][4] = {};
#pragma unroll
  for (int mt = 0; mt < 4; ++mt) {
    const size_t tq = (size_t)((mb >> 4) + mt);
#pragma unroll
    for (int nt = 0; nt < 4; ++nt) {
      const size_t tj   = (size_t)((nb >> 5) + (nt >> 1));
      const size_t base = (tq * 256 + tj) * 512
                        + (size_t)(((nt*2 + (c>>3)) & 3) * 128 + quad*32 + (c & 7));
#pragma unroll
      for (int r = 0; r < 4; ++r) {
        const float p = __expf(acc[mt][nt][r] * 0.0625f);
        psum[mt][r] += p;
        if constexpr (P16) {
          ((_Float16*)Pout)[base + r*8] = (_Float16)p;
        } else {
          const size_t idx = (size_t)(mb + mt*16 + quad*4 + r) * NSEQ + nb + nt*16 + c;
          ((float*)Pout)[idx] = p;
        }
      }
    }
  }

#pragma unroll
  for (int mt = 0; mt < 4; ++mt)
#pragma unroll
    for (int r = 0; r < 4; ++r) {
      float v = psum[mt][r];
      v += __shfl_xor(v, 1);
      v += __shfl_xor(v, 2);
      v += __shfl_xor(v, 4);
      v += __shfl_xor(v, 8);
      if (c == 0) atomicAdd(&lsum[mb + mt*16 + quad*4 + r], v);
    }
}

// ---------------------------------------------------------------------------
// k3a: pv_gemm + fused attn write. cpart[gy] = p @ V over this group's
// K-range; attn = p/lsum written from the staged LDS tiles (each P16F tile
// passes through exactly one block's LDS across the grid -> every attn
// element written exactly once; saves norm_kernel's 128MB P16F re-read and
// a kernel launch). Write mapping: thread (nq=tid>>2, octets tid&3, +4);
// one wave = 16 rows x 256B in 8 adjacent stores -> sector-clean (R3 lesson).
// ---------------------------------------------------------------------------
__global__ __launch_bounds__(256) void pv_gemm_kernel(
    const _Float16* __restrict__ P16F, const _Float16* __restrict__ VT,
    const float* __restrict__ lsum, float* __restrict__ attn,
    float* __restrict__ cpart, int jlen)
{
  __shared__ alignas(16) _Float16 As[2][8][512];
  __shared__ float linv[64];
  const int tid  = threadIdx.x;
  const int lane = tid & 63;
  const int wave = tid >> 6;
  const int c    = lane & 15;
  const int quad = lane >> 4;
  const int M0   = blockIdx.x * 64;
  const int gy   = blockIdx.y;
  const int jb   = gy * jlen;
  const int D0   = wave * 64;
  const size_t tqA = (size_t)(M0 >> 4);
  const int nq   = tid >> 2;            // attn row 0..63
  const int g0   = tid & 3;             // attn j-octets g0, g0+4

  auto stage = [&](int buf, int j0) {
    const size_t tj0 = (size_t)(j0 >> 5);
#pragma unroll
    for (int s = 0; s < 2; ++s) {
      const int t = wave * 2 + s;          // t = mt*2 + ks
      const _Float16* src = &P16F[((tqA + (t >> 1)) * 256 + tj0 + (t & 1)) * 512 + lane * 8];
      __builtin_amdgcn_global_load_lds((gptr_t)src, (lptr_t)&As[buf][t][0], 16, 0, 0);
    }
  };

  if (tid < 64) linv[tid] = 1.0f / lsum[M0 + tid];

  f32x4 acc[4][4] = {};
  stage(0, jb);
  __syncthreads();
  const float nscale = linv[nq];

  const int iters = jlen >> 6;
  for (int it = 0; it < iters; ++it) {
    const int buf = it & 1;
    const int j0  = jb + it * 64;
    if (it + 1 < iters) stage(buf ^ 1, j0 + 64);

    half8 af[4][2];
#pragma unroll
    for (int mt = 0; mt < 4; ++mt)
#pragma unroll
      for (int ks = 0; ks < 2; ++ks)
        af[mt][ks] = *(const half8*)&As[buf][mt*2 + ks][lane * 8];

    half8 bf[4][2];
#pragma unroll
    for (int ks = 0; ks < 2; ++ks)
#pragma unroll
      for (int nt = 0; nt < 4; ++nt)
        bf[nt][ks] = *(const half8*)&VT[(size_t)(D0 + nt*16 + c) * NSEQ + j0 + ks*32 + quad*8];

    // fused attn write from the staged tiles (row-contiguous, sector-clean)
#pragma unroll
    for (int h = 0; h < 2; ++h) {
      const int g = g0 + h*4;
      const int t = ((nq >> 4) << 1) + (g >> 2);
      const half8 v = *(const half8*)&As[buf][t][((g & 3) * 16 + (nq & 15)) * 8];
      f32x4 w0, w1;
#pragma unroll
      for (int r = 0; r < 4; ++r) {
        w0[r] = (float)v[r]     * nscale;
        w1[r] = (float)v[r + 4] * nscale;
      }
      float* ar = attn + (size_t)(M0 + nq) * NSEQ + j0 + g*8;
      *(f32x4*)ar       = w0;
      *(f32x4*)(ar + 4) = w1;
    }

#pragma unroll
    for (int ks = 0; ks < 2; ++ks)
#pragma unroll
      for (int mt = 0; mt < 4; ++mt)
#pragma unroll
        for (int nt = 0; nt < 4; ++nt)
          acc[mt][nt] = __builtin_amdgcn_mfma_f32_16x16x32_f16(af[mt][ks], bf[nt][ks], acc[mt][nt], 0, 0, 0);
    __syncthreads();
  }

  float* out = cpart + (size_t)gy * NSEQ * D_MODEL;
#pragma unroll
  for (int mt = 0; mt < 4; ++mt)
#pragma unroll
    for (int nt = 0; nt < 4; ++nt)
#pragma unroll
      for (int r = 0; r < 4; ++r)
        out[(size_t)(M0 + mt*16 + quad*4 + r) * D_MODEL + D0 + nt*16 + c] = acc[mt][nt][r];
}

// ---------------------------------------------------------------------------
// k3c: reduce — cntx = (sum_g cpart[g]) * (1/lsum[row]).
// ---------------------------------------------------------------------------
__global__ __launch_bounds__(256, 8) void reduce_kernel(
    const float* __restrict__ cpart, const float* __restrict__ lsum,
    float* __restrict__ cntx, int g)
{
  const int idx4 = blockIdx.x * 256 + threadIdx.x;      // f32x4 index
  const int row  = idx4 >> 6;
  const float s  = 1.0f / lsum[row];
  f32x4 v = {};
  for (int gi = 0; gi < g; ++gi)
    v += *(const f32x4*)&cpart[(size_t)gi * NSEQ * D_MODEL + (size_t)idx4 * 4];
  *(f32x4*)&cntx[(size_t)idx4 * 4] = v * s;
}

// ---------------------------------------------------------------------------
// Tier B fallback: R6 fused pv (atomics) — unchanged, known-passing.
// ---------------------------------------------------------------------------
__global__ __launch_bounds__(256) void pv_kernel_p16(
    const _Float16* __restrict__ P16F, float* __restrict__ attn,
    const float* __restrict__ lsum, const _Float16* __restrict__ VT,
    float* __restrict__ cntx)
{
  const int tid  = threadIdx.x;
  const int lane = tid & 63;
  const int wave = tid >> 6;
  const int c    = lane & 15;
  const int quad = lane >> 4;
  const int M0   = blockIdx.x * 32;
  const int jb   = blockIdx.y * (NSEQ / PV_GROUPS);
  const int je   = jb + NSEQ / PV_GROUPS;
  const int D0   = wave * 64;
  const int nq   = tid >> 3;
  const int ng   = tid & 7;

  const float nscale = 1.0f / lsum[M0 + nq];
  const size_t tqA = (size_t)(M0 >> 4);
  const size_t tqN = (size_t)((M0 + nq) >> 4);
  const int    ofsN = ((ng & 3) * 16 + ((M0 + nq) & 15)) * 8;

  f32x4 acc[2][4] = {};
  for (int j0 = jb; j0 < je; j0 += 64) {
    const size_t tj0 = (size_t)(j0 >> 5);
    half8 af[2][2];
#pragma unroll
    for (int mt = 0; mt < 2; ++mt)
#pragma unroll
      for (int ks = 0; ks < 2; ++ks)
        af[mt][ks] = *(const half8*)&P16F[((tqA + mt) * 256 + tj0 + ks) * 512 + lane * 8];
    half8 bf[4][2];
#pragma unroll
    for (int ks = 0; ks < 2; ++ks)
#pragma unroll
      for (int nt = 0; nt < 4; ++nt)
        bf[nt][ks] = *(const half8*)&VT[(size_t)(D0 + nt*16 + c) * NSEQ + j0 + ks*32 + quad*8];
    {
      const half8 v = *(const half8*)&P16F[(tqN * 256 + tj0 + (ng >> 2)) * 512 + ofsN];
      f32x4 w0, w1;
#pragma unroll
      for (int r = 0; r < 4; ++r) {
        w0[r] = (float)v[r]     * nscale;
        w1[r] = (float)v[r + 4] * nscale;
      }
      float* ar = attn + (size_t)(M0 + nq) * NSEQ + j0 + ng*8;
      *(f32x4*)ar       = w0;
      *(f32x4*)(ar + 4) = w1;
    }
#pragma unroll
    for (int ks = 0; ks < 2; ++ks)
#pragma unroll
      for (int mt = 0; mt < 2; ++mt)
#pragma unroll
        for (int nt = 0; nt < 4; ++nt)
          acc[mt][nt] = __builtin_amdgcn_mfma_f32_16x16x32_f16(af[mt][ks], bf[nt][ks], acc[mt][nt], 0, 0, 0);
  }

#pragma unroll
  for (int mt = 0; mt < 2; ++mt)
#pragma unroll
    for (int r = 0; r < 4; ++r) {
      const float s = 1.0f / lsum[M0 + mt*16 + quad*4 + r];
#pragma unroll
      for (int nt = 0; nt < 4; ++nt)
        atomicAdd(&cntx[(size_t)(M0 + mt*16 + quad*4 + r) * D_MODEL + D0 + nt*16 + c],
                  acc[mt][nt][r] * s);
    }
}

// ---------------------------------------------------------------------------
// Tier C fallback (small ws): in-place f32 normalize + PV.
// ---------------------------------------------------------------------------
__global__ __launch_bounds__(256) void pv_kernel_f32(
    const float* __restrict__ Pin, float* __restrict__ attn,
    const float* __restrict__ lsum, const _Float16* __restrict__ VT,
    float* __restrict__ cntx)
{
  __shared__ float linv[32];
  const int tid  = threadIdx.x;
  const int lane = tid & 63;
  const int wave = tid >> 6;
  const int c    = lane & 15;
  const int quad = lane >> 4;
  const int M0   = blockIdx.x * 32;
  const int jb   = blockIdx.y * (NSEQ / PV_GROUPS);
  const int je   = jb + NSEQ / PV_GROUPS;
  const int D0   = wave * 64;
  const int nr   = tid >> 3;
  const int ncol = (tid & 7) * 8;

  if (tid < 32) linv[tid] = 1.0f / lsum[M0 + tid];
  __syncthreads();
  const float nscale = linv[nr];

  f32x4 acc[2][4] = {};
  for (int j0 = jb; j0 < je; j0 += 64) {
    const float* pr = Pin + (size_t)(M0 + nr) * NSEQ + j0 + ncol;
    f32x4 np0 = *(const f32x4*)pr;
    f32x4 np1 = *(const f32x4*)(pr + 4);

    half8 af[2][2], bf[4][2];
#pragma unroll
    for (int h = 0; h < 2; ++h) {
#pragma unroll
      for (int mt = 0; mt < 2; ++mt) {
        const float* pa = Pin + (size_t)(M0 + mt*16 + c) * NSEQ + j0 + h*32 + quad*8;
        af[mt][h] = cvt8(*(const f32x4*)pa, *(const f32x4*)(pa + 4));
      }
#pragma unroll
      for (int nt = 0; nt < 4; ++nt)
        bf[nt][h] = *(const half8*)&VT[(size_t)(D0 + nt*16 + c) * NSEQ + j0 + h*32 + quad*8];
    }

    __syncthreads();

    float* ar = attn + (size_t)(M0 + nr) * NSEQ + j0 + ncol;
    *(f32x4*)ar       = np0 * nscale;
    *(f32x4*)(ar + 4) = np1 * nscale;

#pragma unroll
    for (int h = 0; h < 2; ++h)
#pragma unroll
      for (int mt = 0; mt < 2; ++mt)
#pragma unroll
        for (int nt = 0; nt < 4; ++nt)
          acc[mt][nt] = __builtin_amdgcn_mfma_f32_16x16x32_f16(af[mt][h], bf[nt][h], acc[mt][nt], 0, 0, 0);
  }

#pragma unroll
  for (int mt = 0; mt < 2; ++mt)
#pragma unroll
    for (int r = 0; r < 4; ++r) {
      const float s = linv[mt*16 + quad*4 + r];
#pragma unroll
      for (int nt = 0; nt < 4; ++nt)
        atomicAdd(&cntx[(size_t)(M0 + mt*16 + quad*4 + r) * D_MODEL + D0 + nt*16 + c],
                  acc[mt][nt][r] * s);
    }
}

// ---------------------------------------------------------------------------
extern "C" void kernel_launch(void* const* d_in, const int* in_sizes, int n_in,
                              void* d_out, int out_size, void* d_ws, size_t ws_size,
                              hipStream_t stream)
{
  const float* x  = (const float*)d_in[0];
  const float* Wq = (const float*)d_in[1];
  const float* Wk = (const float*)d_in[2];
  const float* Wv = (const float*)d_in[3];

  float* cntx = (float*)d_out;                         // [8192 x 256]
  float* attn = cntx + (size_t)NSEQ * D_MODEL;         // [8192 x 8192]

  // ws layout: QK16 (8MB) | VT (4MB) | lsum (32KB) | P16F (128MB) | cpart (g*8MB)
  _Float16* QK16 = (_Float16*)d_ws;
  _Float16* VT   = QK16 + (size_t)NSEQ * 512;
  float*    lsum = (float*)(VT + (size_t)D_MODEL * NSEQ);
  _Float16* P16F = (_Float16*)(lsum + NSEQ);
  float*    cpart = (float*)(P16F + (size_t)NSEQ * NSEQ);

  const size_t base_bytes = (size_t)NSEQ*512*2 + (size_t)D_MODEL*NSEQ*2 + (size_t)NSEQ*4;
  const size_t p16_bytes  = (size_t)NSEQ * NSEQ * 2;
  const size_t part_bytes = (size_t)NSEQ * D_MODEL * 4;   // 8MB per group

  int g = 0;
  for (int gt = 8; gt >= 2; gt >>= 1)
    if (ws_size >= base_bytes + p16_bytes + (size_t)gt * part_bytes) { g = gt; break; }
  const bool big_ws = ws_size >= base_bytes + p16_bytes;

  hipMemsetAsync(lsum, 0, sizeof(float) * NSEQ, stream);

  qkv_kernel<<<dim3(256, 24), 64, 0, stream>>>(x, Wq, Wk, Wv, QK16, VT);

  if (g >= 2) {
    // Tier A: no atomics; attn write fused into pv_gemm (norm kernel removed)
    score_kernel<true><<<dim3(64, 64), 256, 0, stream>>>(QK16, (void*)P16F, lsum);
    pv_gemm_kernel<<<dim3(128, g), 256, 0, stream>>>(P16F, VT, lsum, attn, cpart, NSEQ / g);
    reduce_kernel<<<dim3(NSEQ * D_MODEL / 1024), 256, 0, stream>>>(cpart, lsum, cntx, g);
  } else if (big_ws) {
    // Tier B: fused pv with atomics (R6 path)
    hipMemsetAsync(cntx, 0, sizeof(float) * (size_t)NSEQ * D_MODEL, stream);
    score_kernel<true><<<dim3(64, 64), 256, 0, stream>>>(QK16, (void*)P16F, lsum);
    pv_kernel_p16<<<dim3(NSEQ/32, PV_GROUPS), 256, 0, stream>>>(P16F, attn, lsum, VT, cntx);
  } else {
    // Tier C: f32 in-place path
    hipMemsetAsync(cntx, 0, sizeof(float) * (size_t)NSEQ * D_MODEL, stream);
    score_kernel<false><<<dim3(64, 64), 256, 0, stream>>>(QK16, (void*)attn, lsum);
    pv_kernel_f32<<<dim3(NSEQ/32, PV_GROUPS), 256, 0, stream>>>(attn, attn, lsum, VT, cntx);
  }
}